// Round 4
// baseline (14264.859 us; speedup 1.0000x reference)
//
#include <hip/hip_runtime.h>
#include <hip/hip_bf16.h>
#include <math.h>

namespace {

constexpr int NU   = 50000;
constexpr int NI   = 30000;
constexpr int D    = 128;
constexpr int EUG  = 2000000;
constexpr int EAND = 1000000;
constexpr int EOR  = 1000000;
constexpr int NB_U = (NU + 63) / 64;   // 782 buckets
constexpr int NB_I = (NI + 63) / 64;   // 469 buckets

// ---------- fused degree counts ----------
struct CountAll {
  const int* idx[10];
  int* cnt[10];
  int n[10];
  int blkbase[11];
};
__global__ __launch_bounds__(256) void count_all_k(CountAll C) {
  int seg = 0;
#pragma unroll
  for (int i = 1; i < 10; ++i) if ((int)blockIdx.x >= C.blkbase[i]) seg = i;
  int t = ((int)blockIdx.x - C.blkbase[seg]) * 256 + (int)threadIdx.x;
  if (t < C.n[seg]) atomicAdd(&C.cnt[seg][C.idx[seg][t]], 1);
}

__global__ void norms_k(const int* __restrict__ cnt, float* __restrict__ inv, int n) {
  int t = blockIdx.x * 256 + threadIdx.x;
  if (t < n) inv[t] = rsqrtf((float)max(cnt[t], 1));
}

// ---------- bucket counts from node counts ----------
struct BsumAll { const int* cnt[6]; int* bcnt[6]; int nnodes[6]; int base[7]; };
__global__ __launch_bounds__(256) void bsum_k(BsumAll B) {
  int t = blockIdx.x * 256 + threadIdx.x;
  if (t >= B.base[6]) return;
  int seg = 0;
#pragma unroll
  for (int i = 1; i < 6; ++i) if (t >= B.base[i]) seg = i;
  int lb = t - B.base[seg];
  int n0 = lb << 6;
  int n1 = min(n0 + 64, B.nnodes[seg]);
  const int* c = B.cnt[seg];
  int s = 0;
  for (int i = n0; i < n1; ++i) s += c[i];
  B.bcnt[seg][lb] = s;
}

// ---------- fused exclusive scans (one workgroup per segment) ----------
struct ScanSeg { const int* cnt; int* off; int* cur; int n; };
struct ScanAll { ScanSeg s[6]; };
__global__ __launch_bounds__(1024) void exscan_multi_k(ScanAll S) {
  ScanSeg sg = S.s[blockIdx.x];
  __shared__ int ts[1024];
  const int t = threadIdx.x;
  const int per = (sg.n + 1023) >> 10;
  const int b = min(t * per, sg.n);
  const int e = min(b + per, sg.n);
  int s = 0;
  for (int i = b; i < e; ++i) s += sg.cnt[i];
  ts[t] = s;
  __syncthreads();
  for (int d = 1; d < 1024; d <<= 1) {
    int v = (t >= d) ? ts[t - d] : 0;
    __syncthreads();
    ts[t] += v;
    __syncthreads();
  }
  if (t == 1023) sg.off[sg.n] = ts[1023];
  int run = (t == 0) ? 0 : ts[t - 1];
  for (int i = b; i < e; ++i) { sg.off[i] = run; sg.cur[i] = run; run += sg.cnt[i]; }
}

// ---------- fused bucket binning ----------
struct BinAll {
  const int* dst[6];
  const int* src[6];
  int* cur[6];            // bucket cursors
  unsigned* ents[6];      // packed (dst&63)<<16 | src
  float* ew0;             // seg0 (UG-u) folded weights
  const float* invG; const float* wn; const float* we;
  int n[6];
  int blkbase[7];
};
__global__ __launch_bounds__(256) void bin_all_k(BinAll F) {
  int seg = 0;
#pragma unroll
  for (int i = 1; i < 6; ++i) if ((int)blockIdx.x >= F.blkbase[i]) seg = i;
  int e = ((int)blockIdx.x - F.blkbase[seg]) * 256 + (int)threadIdx.x;
  if (e >= F.n[seg]) return;
  int dn = F.dst[seg][e], sn = F.src[seg][e];
  int pos = atomicAdd(&F.cur[seg][dn >> 6], 1);
  F.ents[seg][pos] = ((unsigned)(dn & 63) << 16) | (unsigned)sn;
  if (seg == 0) F.ew0[pos] = F.invG[sn] * F.wn[sn] * F.we[e];
}

// ---------- bucketed gather: one block per 64-node bucket, LDS accumulation ----------
struct BJob {
  const float* x; const unsigned* ents; const float* ew; const int* boff;
  const float* invS; const float* invD; float* out; int nrows; int bbeg;
};
struct BJobs { BJob j[6]; };

__global__ __launch_bounds__(256) void bgather_k(BJobs J) {
  __shared__ float acc[64][132];   // +4 pad
  int gb = (int)blockIdx.x;
  BJob jb = J.j[0];
#pragma unroll
  for (int i = 1; i < 6; ++i) if (gb >= J.j[i].bbeg) jb = J.j[i];
  int bk = gb - jb.bbeg;
  int row0 = bk << 6;
  int nr = min(64, jb.nrows - row0);

  float4* az = (float4*)&acc[0][0];
  for (int i = threadIdx.x; i < (64 * 132) / 4; i += 256)
    az[i] = make_float4(0.f, 0.f, 0.f, 0.f);
  __syncthreads();

  int beg = jb.boff[bk], end = jb.boff[bk + 1];
  int len = end - beg;
  int wv = (int)threadIdx.x >> 6;
  int lane = (int)threadIdx.x & 63;
  int lane2 = lane << 1;
  int wbeg = beg + (int)(((long)len * wv) >> 2);
  int wend = beg + (int)(((long)len * (wv + 1)) >> 2);
  const float2* __restrict__ x2 = (const float2*)jb.x;
  const bool hasw = (jb.ew != nullptr);

#define EDGE_BODY(kk)                                                \
  {                                                                  \
    unsigned ds = (unsigned)__shfl((int)myent, (kk));                \
    int row = (int)(ds >> 16);                                       \
    int srn = (int)(ds & 0xffffu);                                   \
    float w = hasw ? __shfl(myw, (kk)) : jb.invS[srn];               \
    float2 v = x2[(size_t)srn * 64 + lane];                          \
    atomicAdd(&acc[row][lane2], w * v.x);                            \
    atomicAdd(&acc[row][lane2 + 1], w * v.y);                        \
  }

  for (int p = wbeg; p < wend; p += 64) {
    int nk = min(64, wend - p);
    unsigned myent = (lane < nk) ? jb.ents[p + lane] : 0u;
    float myw = 0.f;
    if (hasw && lane < nk) myw = jb.ew[p + lane];
    if (nk == 64) {
#pragma unroll 8
      for (int k = 0; k < 64; ++k) EDGE_BODY(k)
    } else {
      for (int k = 0; k < nk; ++k) EDGE_BODY(k)
    }
  }
#undef EDGE_BODY

  __syncthreads();
  for (int i = threadIdx.x; i < nr * 32; i += 256) {
    int r = i >> 5, c4 = i & 31;
    int node = row0 + r;
    float s = jb.invD[node];
    float4 vv = *(float4*)&acc[r][c4 << 2];
    vv.x *= s; vv.y *= s; vv.z *= s; vv.w *= s;
    ((float4*)jb.out)[(size_t)node * 32 + c4] = vv;
  }
}

// ---------- layer attention (unchanged, verified) ----------
struct AttnArgs {
  const float* layer[7];
  float coef[7];
};

__device__ inline void osm_upd(float& m, float& den, float& num, float sc, float tv) {
  float nm = fmaxf(m, sc);
  float e0 = __expf(m - nm);
  float e1 = __expf(sc - nm);
  den = den * e0 + e1;
  num = num * e0 + tv * e1;
  m = nm;
}

template <int L>
__global__ __launch_bounds__(256) void attn_k(AttnArgs args,
    const float* __restrict__ W, const float* __restrict__ avec,
    float* __restrict__ out, float out_scale, int beta,
    const float* __restrict__ extra, float escale, int n) {
  __shared__ float4 Ws4[2048];
  __shared__ float xs[32][132];
  const int tid = threadIdx.x;
  const int dt = tid & 15;
  const int grp = tid >> 4;
  const int half = blockIdx.y;
  const int base = blockIdx.x * 32;
  const float4* __restrict__ W4 = (const float4*)W;

  for (int i = tid; i < 2048; i += 256) {
    int k = i >> 4, d = i & 15;
    Ws4[i] = W4[(k << 5) + (half << 4) + d];
  }
  const float4 a4 = ((const float4*)avec)[(half << 4) + dt];
  const float am[4] = {a4.x, a4.y, a4.z, a4.w};

  float m[2][4], den[2][4], num[2][4];
#pragma unroll
  for (int g = 0; g < 2; ++g)
#pragma unroll
    for (int c = 0; c < 4; ++c) { m[g][c] = -3.0e38f; den[g][c] = 0.f; num[g][c] = 0.f; }

#pragma unroll
  for (int l = 0; l < L; ++l) {
    __syncthreads();
    const float4* __restrict__ L4 = (const float4*)args.layer[l];
    for (int i = tid; i < 1024; i += 256) {
      int r = i >> 5, c4 = i & 31;
      int node = base + r;
      float4 v = (node < n) ? L4[(size_t)node * 32 + c4] : make_float4(0.f, 0.f, 0.f, 0.f);
      *(float4*)&xs[r][c4 << 2] = v;
    }
    __syncthreads();
    float s0[4] = {0.f, 0.f, 0.f, 0.f}, s1[4] = {0.f, 0.f, 0.f, 0.f};
#pragma unroll 4
    for (int k = 0; k < 128; ++k) {
      float4 w = Ws4[(k << 4) + dt];
      float x0 = xs[grp][k];
      float x1 = xs[grp + 16][k];
      s0[0] = fmaf(x0, w.x, s0[0]); s0[1] = fmaf(x0, w.y, s0[1]);
      s0[2] = fmaf(x0, w.z, s0[2]); s0[3] = fmaf(x0, w.w, s0[3]);
      s1[0] = fmaf(x1, w.x, s1[0]); s1[1] = fmaf(x1, w.y, s1[1]);
      s1[2] = fmaf(x1, w.z, s1[2]); s1[3] = fmaf(x1, w.w, s1[3]);
    }
    float c = args.coef[l];
    float4 t0 = *(const float4*)&xs[grp][(half << 6) + (dt << 2)];
    float4 t1 = *(const float4*)&xs[grp + 16][(half << 6) + (dt << 2)];
    const float tv0[4] = {t0.x, t0.y, t0.z, t0.w};
    const float tv1[4] = {t1.x, t1.y, t1.z, t1.w};
#pragma unroll
    for (int ch = 0; ch < 4; ++ch) {
      osm_upd(m[0][ch], den[0][ch], num[0][ch], c * s0[ch] * am[ch], c * tv0[ch]);
      osm_upd(m[1][ch], den[1][ch], num[1][ch], c * s1[ch] * am[ch], c * tv1[ch]);
    }
  }
#pragma unroll
  for (int g = 0; g < 2; ++g) {
    int node = base + grp + g * 16;
    if (node >= n) continue;
    float4 o;
    o.x = num[g][0] / den[g][0];
    o.y = num[g][1] / den[g][1];
    o.z = num[g][2] / den[g][2];
    o.w = num[g][3] / den[g][3];
    size_t oi = (size_t)node * 32 + (half << 4) + dt;
    float4* op = (float4*)out + oi;
    if (beta) {
      float4 pv = *op;
      float4 ev = extra ? ((const float4*)extra)[oi] : make_float4(0.f, 0.f, 0.f, 0.f);
      o.x = pv.x + out_scale * o.x + escale * ev.x;
      o.y = pv.y + out_scale * o.y + escale * ev.y;
      o.z = pv.z + out_scale * o.z + escale * ev.z;
      o.w = pv.w + out_scale * o.w + escale * ev.w;
    } else {
      o.x *= out_scale; o.y *= out_scale; o.z *= out_scale; o.w *= out_scale;
    }
    *op = o;
  }
}

inline dim3 g1(long n) { return dim3((unsigned)((n + 255) / 256)); }

} // namespace

extern "C" void kernel_launch(void* const* d_in, const int* in_sizes, int n_in,
                              void* d_out, int out_size, void* d_ws, size_t ws_size,
                              hipStream_t stream) {
  const int* ug_u = (const int*)d_in[0];
  const int* ug_g = (const int*)d_in[1];
  const int* aS[3] = {(const int*)d_in[2], (const int*)d_in[4], (const int*)d_in[6]};
  const int* aD[3] = {(const int*)d_in[3], (const int*)d_in[5], (const int*)d_in[7]};
  const int* oS = (const int*)d_in[8];
  const int* oD = (const int*)d_in[9];
  const float* ue    = (const float*)d_in[10];
  const float* ie    = (const float*)d_in[11];
  const float* W_and = (const float*)d_in[12];
  const float* a_and = (const float*)d_in[13];
  const float* W_or  = (const float*)d_in[14];
  const float* a_or  = (const float*)d_in[15];
  const float* wedge = (const float*)d_in[16];
  const float* wnode = (const float*)d_in[17];

  // ---- workspace carve-up ----
  char* basep = (char*)d_ws;
  size_t boff_ = 0;
  auto alloc = [&](size_t bytes) -> void* {
    void* r = basep + boff_;
    boff_ += (bytes + 15) & ~(size_t)15;
    return r;
  };

  const int NCNT = NU + 9 * NI;
  int* cnt_all = (int*)alloc((size_t)NCNT * 4);
  float* inv_all = (float*)alloc((size_t)NCNT * 4);
  int* cU = cnt_all;
  int* cG = cU + NU;
  int* cAs[3], *cAd[3];
  { int* p = cG + NI;
    for (int i = 0; i < 3; ++i) { cAs[i] = p; p += NI; cAd[i] = p; p += NI; } }
  int* cOs = cAd[2] + NI;
  int* cOd = cOs + NI;
  float* invU = inv_all;
  float* invG = invU + NU;
  float* iAo[3], *iAi[3];
  { float* p = invG + NI;
    for (int i = 0; i < 3; ++i) { iAo[i] = p; p += NI; iAi[i] = p; p += NI; } }
  float* iOo = iAi[2] + NI;
  float* iOi = iOo + NI;

  // bucket arrays: seg order = {UGu(by u), UGg(by g), AND0, AND1, AND2, OR}
  const int nbs[6] = {NB_U, NB_I, NB_I, NB_I, NB_I, NB_I};
  int* bcnt[6]; int* bofs[6]; int* bcur[6];
  for (int i = 0; i < 6; ++i) {
    bcnt[i] = (int*)alloc((size_t)nbs[i] * 4);
    bofs[i] = (int*)alloc((size_t)(nbs[i] + 1) * 4);
    bcur[i] = (int*)alloc((size_t)nbs[i] * 4);
  }

  unsigned* eUGu = (unsigned*)alloc((size_t)EUG * 4);
  float*    wUGu = (float*)alloc((size_t)EUG * 4);
  unsigned* eUGg = (unsigned*)alloc((size_t)EUG * 4);
  unsigned* eAnd[3]; for (int i = 0; i < 3; ++i) eAnd[i] = (unsigned*)alloc((size_t)EAND * 4);
  unsigned* eOr = (unsigned*)alloc((size_t)EOR * 4);

  float* hu1 = (float*)alloc((size_t)NU * D * 4);
  float* hg1 = (float*)alloc((size_t)NI * D * 4);
  float* hg2 = (float*)alloc((size_t)NI * D * 4);
  float* ab[6]; for (int i = 0; i < 6; ++i) ab[i] = (float*)alloc((size_t)NI * D * 4);
  float* ob[3]; for (int i = 0; i < 3; ++i) ob[i] = (float*)alloc((size_t)NI * D * 4);

  float* out_hu = (float*)d_out;
  float* out_game = out_hu + (size_t)NU * D;

  // ---- degrees ----
  hipMemsetAsync(cnt_all, 0, (size_t)NCNT * 4, stream);
  CountAll C{};
  {
    const int* idxs[10] = {ug_u, ug_g, aS[0], aD[0], aS[1], aD[1], aS[2], aD[2], oS, oD};
    int* cnts[10] = {cU, cG, cAs[0], cAd[0], cAs[1], cAd[1], cAs[2], cAd[2], cOs, cOd};
    int ns[10] = {EUG, EUG, EAND, EAND, EAND, EAND, EAND, EAND, EOR, EOR};
    int bb = 0;
    for (int i = 0; i < 10; ++i) {
      C.idx[i] = idxs[i]; C.cnt[i] = cnts[i]; C.n[i] = ns[i];
      C.blkbase[i] = bb; bb += (ns[i] + 255) / 256;
    }
    C.blkbase[10] = bb;
  }
  count_all_k<<<dim3(C.blkbase[10]), 256, 0, stream>>>(C);
  norms_k<<<g1(NCNT), 256, 0, stream>>>(cnt_all, inv_all, NCNT);

  // ---- bucket counts ----
  BsumAll BS{};
  {
    const int* ncs[6] = {cU, cG, cAd[0], cAd[1], cAd[2], cOd};
    int nn[6] = {NU, NI, NI, NI, NI, NI};
    int bb = 0;
    for (int i = 0; i < 6; ++i) {
      BS.cnt[i] = ncs[i]; BS.bcnt[i] = bcnt[i]; BS.nnodes[i] = nn[i];
      BS.base[i] = bb; bb += nbs[i];
    }
    BS.base[6] = bb;
  }
  bsum_k<<<g1(BS.base[6]), 256, 0, stream>>>(BS);

  // ---- bucket offsets + cursors ----
  ScanAll SA{};
  for (int i = 0; i < 6; ++i) SA.s[i] = {bcnt[i], bofs[i], bcur[i], nbs[i]};
  exscan_multi_k<<<dim3(6), 1024, 0, stream>>>(SA);

  // ---- bin edges into buckets ----
  BinAll F{};
  {
    const int* ds[6] = {ug_u, ug_g, aD[0], aD[1], aD[2], oD};
    const int* ss[6] = {ug_g, ug_u, aS[0], aS[1], aS[2], oS};
    unsigned* es[6] = {eUGu, eUGg, eAnd[0], eAnd[1], eAnd[2], eOr};
    int ns[6] = {EUG, EUG, EAND, EAND, EAND, EOR};
    int bb = 0;
    for (int i = 0; i < 6; ++i) {
      F.dst[i] = ds[i]; F.src[i] = ss[i]; F.cur[i] = bcur[i]; F.ents[i] = es[i]; F.n[i] = ns[i];
      F.blkbase[i] = bb; bb += (ns[i] + 255) / 256;
    }
    F.blkbase[6] = bb;
    F.ew0 = wUGu; F.invG = invG; F.wn = wnode; F.we = wedge;
  }
  bin_all_k<<<dim3(F.blkbase[6]), 256, 0, stream>>>(F);

  // ---- gathers (bucketed, fused multi-job) ----
  auto launch_bg = [&](BJob* jobs, int nj) {
    BJobs J{};
    int bb = 0;
    for (int k = 0; k < nj; ++k) {
      J.j[k] = jobs[k];
      J.j[k].bbeg = bb;
      bb += (jobs[k].nrows + 63) / 64;
    }
    for (int k = nj; k < 6; ++k) { J.j[k] = J.j[0]; J.j[k].bbeg = 0x7fffffff; }
    bgather_k<<<dim3(bb), 256, 0, stream>>>(J);
  };

  // G1: hu1<-ie (UGu), hg1<-ue (UGg), ab0..2<-ie (AND), ob0<-ie (OR)
  {
    BJob js[6] = {
      {ie, eUGu, wUGu, bofs[0], nullptr, invU, hu1, NU, 0},
      {ue, eUGg, nullptr, bofs[1], invU, invG, hg1, NI, 0},
      {ie, eAnd[0], nullptr, bofs[2], iAo[0], iAi[0], ab[0], NI, 0},
      {ie, eAnd[1], nullptr, bofs[3], iAo[1], iAi[1], ab[1], NI, 0},
      {ie, eAnd[2], nullptr, bofs[4], iAo[2], iAi[2], ab[2], NI, 0},
      {ie, eOr, nullptr, bofs[5], iOo, iOi, ob[0], NI, 0},
    };
    launch_bg(js, 6);
  }
  // G2: out_hu<-hg1, hg2<-hu1, ab3..5<-ab0..2, ob1<-ob0
  {
    BJob js[6] = {
      {hg1, eUGu, wUGu, bofs[0], nullptr, invU, out_hu, NU, 0},
      {hu1, eUGg, nullptr, bofs[1], invU, invG, hg2, NI, 0},
      {ab[0], eAnd[0], nullptr, bofs[2], iAo[0], iAi[0], ab[3], NI, 0},
      {ab[1], eAnd[1], nullptr, bofs[3], iAo[1], iAi[1], ab[4], NI, 0},
      {ab[2], eAnd[2], nullptr, bofs[4], iAo[2], iAi[2], ab[5], NI, 0},
      {ob[0], eOr, nullptr, bofs[5], iOo, iOi, ob[1], NI, 0},
    };
    launch_bg(js, 6);
  }
  // G3: ob2<-ob1
  {
    BJob js[1] = {{ob[1], eOr, nullptr, bofs[5], iOo, iOi, ob[2], NI, 0}};
    launch_bg(js, 1);
  }

  const float w_or = 80.0f / 82.0f;
  const float w_and = w_or / 80.0f;   // = 1/82
  const float w_self = w_and;

  // ---- layer attention ----
  AttnArgs aa{};
  aa.layer[0] = ie;
  for (int i = 0; i < 6; ++i) aa.layer[1 + i] = ab[i];
  for (int i = 0; i < 7; ++i) aa.coef[i] = 1.0f;
  attn_k<7><<<dim3((NI + 31) / 32, 2), 256, 0, stream>>>(
      aa, W_and, a_and, out_game, w_and, 0, nullptr, 0.f, NI);

  AttnArgs ao{};
  ao.layer[0] = ie; ao.layer[1] = ob[0]; ao.layer[2] = ob[1]; ao.layer[3] = ob[2];
  ao.coef[0] = 1.0f; ao.coef[1] = 0.6f; ao.coef[2] = 0.8f; ao.coef[3] = 1.0f;
  attn_k<4><<<dim3((NI + 31) / 32, 2), 256, 0, stream>>>(
      ao, W_or, a_or, out_game, w_or, 1, hg2, w_self, NI);
}

// Round 5
// 2347.232 us; speedup vs baseline: 6.0773x; 6.0773x over previous
//
#include <hip/hip_runtime.h>
#include <hip/hip_bf16.h>
#include <math.h>

namespace {

constexpr int NU   = 50000;
constexpr int NI   = 30000;
constexpr int D    = 128;
constexpr int EUG  = 2000000;
constexpr int EAND = 1000000;
constexpr int EOR  = 1000000;
constexpr int NPASS = 3;   // windowed fill passes

// ---------- fused degree counts ----------
struct CountAll {
  const int* idx[10];
  int* cnt[10];
  int n[10];
  int blkbase[11];
};
__global__ __launch_bounds__(256) void count_all_k(CountAll C) {
  int seg = 0;
#pragma unroll
  for (int i = 1; i < 10; ++i) if ((int)blockIdx.x >= C.blkbase[i]) seg = i;
  int t = ((int)blockIdx.x - C.blkbase[seg]) * 256 + (int)threadIdx.x;
  if (t < C.n[seg]) atomicAdd(&C.cnt[seg][C.idx[seg][t]], 1);
}

__global__ void norms_k(const int* __restrict__ cnt, float* __restrict__ inv, int n) {
  int t = blockIdx.x * 256 + threadIdx.x;
  if (t < n) inv[t] = rsqrtf((float)max(cnt[t], 1));
}

// ---------- fused exclusive scans (one workgroup per segment) ----------
struct ScanSeg { const int* cnt; int* off; int* cur; int n; };
struct ScanAll { ScanSeg s[6]; };
__global__ __launch_bounds__(1024) void exscan_multi_k(ScanAll S) {
  ScanSeg sg = S.s[blockIdx.x];
  __shared__ int ts[1024];
  const int t = threadIdx.x;
  const int per = (sg.n + 1023) >> 10;
  const int b = min(t * per, sg.n);
  const int e = min(b + per, sg.n);
  int s = 0;
  for (int i = b; i < e; ++i) s += sg.cnt[i];
  ts[t] = s;
  __syncthreads();
  for (int d = 1; d < 1024; d <<= 1) {
    int v = (t >= d) ? ts[t - d] : 0;
    __syncthreads();
    ts[t] += v;
    __syncthreads();
  }
  if (t == 1023) sg.off[sg.n] = ts[1023];
  int run = (t == 0) ? 0 : ts[t - 1];
  for (int i = b; i < e; ++i) { sg.off[i] = run; sg.cur[i] = run; run += sg.cnt[i]; }
}

// ---------- windowed CSR fill (pass p only handles dst in [wbeg,wend)) ----------
struct FillWin {
  const int* dst[6];
  const int* src[6];
  int* cur[6];
  int* csrc[6];
  float* cwt;           // segment 0 only (UG user side)
  const float* invS0;   // invG
  const float* wn0;
  const float* we0;
  int n[6];
  int wbeg[6];
  int wend[6];
  int blkbase[7];
};
__global__ __launch_bounds__(256) void fill_win_k(FillWin F) {
  int seg = 0;
#pragma unroll
  for (int i = 1; i < 6; ++i) if ((int)blockIdx.x >= F.blkbase[i]) seg = i;
  int e = ((int)blockIdx.x - F.blkbase[seg]) * 256 + (int)threadIdx.x;
  if (e >= F.n[seg]) return;
  int dn = F.dst[seg][e];
  if (dn < F.wbeg[seg] || dn >= F.wend[seg]) return;
  int sn = F.src[seg][e];
  int pos = atomicAdd(&F.cur[seg][dn], 1);
  F.csrc[seg][pos] = sn;
  if (seg == 0) F.cwt[pos] = F.invS0[sn] * F.wn0[sn] * F.we0[e];
}

// ---------- multi-job pull aggregation: one 64-lane wave per dst row ----------
struct GJob {
  const float* x; const int* roff; const int* csrc; const float* cwt;
  const float* invS; const float* invD; float* out; int rbeg;
};
struct GJobs { GJob j[6]; int total; };

__global__ __launch_bounds__(256) void gather_multi_k(GJobs J) {
  int wid = ((int)blockIdx.x << 2) | ((int)threadIdx.x >> 6);
  if (wid >= J.total) return;
  GJob jb = J.j[0];
#pragma unroll
  for (int i = 1; i < 6; ++i) if (wid >= J.j[i].rbeg) jb = J.j[i];
  int row = wid - jb.rbeg;
  int lane = (int)threadIdx.x & 63;
  int beg = __builtin_amdgcn_readfirstlane(jb.roff[row]);
  int end = __builtin_amdgcn_readfirstlane(jb.roff[row + 1]);
  const float2* __restrict__ x2 = (const float2*)jb.x;
  const int* __restrict__ cs = jb.csrc;
  float ax = 0.f, ay = 0.f;
  int j = beg;
  if (jb.cwt) {
    const float* __restrict__ cw = jb.cwt;
    for (; j + 7 < end; j += 8) {
      int s[8]; float w[8];
#pragma unroll
      for (int k = 0; k < 8; ++k) { s[k] = cs[j + k]; w[k] = cw[j + k]; }
#pragma unroll
      for (int k = 0; k < 8; ++k) {
        float2 v = x2[(size_t)s[k] * 64 + lane];
        ax = fmaf(w[k], v.x, ax); ay = fmaf(w[k], v.y, ay);
      }
    }
    for (; j < end; ++j) {
      int s = cs[j]; float w = cw[j];
      float2 v = x2[(size_t)s * 64 + lane];
      ax = fmaf(w, v.x, ax); ay = fmaf(w, v.y, ay);
    }
  } else {
    const float* __restrict__ is = jb.invS;
    for (; j + 7 < end; j += 8) {
      int s[8]; float w[8];
#pragma unroll
      for (int k = 0; k < 8; ++k) { s[k] = cs[j + k]; w[k] = is[s[k]]; }
#pragma unroll
      for (int k = 0; k < 8; ++k) {
        float2 v = x2[(size_t)s[k] * 64 + lane];
        ax = fmaf(w[k], v.x, ax); ay = fmaf(w[k], v.y, ay);
      }
    }
    for (; j < end; ++j) {
      int s = cs[j]; float w = is[s];
      float2 v = x2[(size_t)s * 64 + lane];
      ax = fmaf(w, v.x, ax); ay = fmaf(w, v.y, ay);
    }
  }
  float si = jb.invD[row];
  float2 o; o.x = ax * si; o.y = ay * si;
  ((float2*)jb.out)[(size_t)row * 64 + lane] = o;
}

// ---------- layer attention (verified since round 2) ----------
struct AttnArgs {
  const float* layer[7];
  float coef[7];
};

__device__ inline void osm_upd(float& m, float& den, float& num, float sc, float tv) {
  float nm = fmaxf(m, sc);
  float e0 = __expf(m - nm);
  float e1 = __expf(sc - nm);
  den = den * e0 + e1;
  num = num * e0 + tv * e1;
  m = nm;
}

template <int L>
__global__ __launch_bounds__(256) void attn_k(AttnArgs args,
    const float* __restrict__ W, const float* __restrict__ avec,
    float* __restrict__ out, float out_scale, int beta,
    const float* __restrict__ extra, float escale, int n) {
  __shared__ float4 Ws4[2048];
  __shared__ float xs[32][132];
  const int tid = threadIdx.x;
  const int dt = tid & 15;
  const int grp = tid >> 4;
  const int half = blockIdx.y;
  const int base = blockIdx.x * 32;
  const float4* __restrict__ W4 = (const float4*)W;

  for (int i = tid; i < 2048; i += 256) {
    int k = i >> 4, d = i & 15;
    Ws4[i] = W4[(k << 5) + (half << 4) + d];
  }
  const float4 a4 = ((const float4*)avec)[(half << 4) + dt];
  const float am[4] = {a4.x, a4.y, a4.z, a4.w};

  float m[2][4], den[2][4], num[2][4];
#pragma unroll
  for (int g = 0; g < 2; ++g)
#pragma unroll
    for (int c = 0; c < 4; ++c) { m[g][c] = -3.0e38f; den[g][c] = 0.f; num[g][c] = 0.f; }

#pragma unroll
  for (int l = 0; l < L; ++l) {
    __syncthreads();
    const float4* __restrict__ L4 = (const float4*)args.layer[l];
    for (int i = tid; i < 1024; i += 256) {
      int r = i >> 5, c4 = i & 31;
      int node = base + r;
      float4 v = (node < n) ? L4[(size_t)node * 32 + c4] : make_float4(0.f, 0.f, 0.f, 0.f);
      *(float4*)&xs[r][c4 << 2] = v;
    }
    __syncthreads();
    float s0[4] = {0.f, 0.f, 0.f, 0.f}, s1[4] = {0.f, 0.f, 0.f, 0.f};
#pragma unroll 4
    for (int k = 0; k < 128; ++k) {
      float4 w = Ws4[(k << 4) + dt];
      float x0 = xs[grp][k];
      float x1 = xs[grp + 16][k];
      s0[0] = fmaf(x0, w.x, s0[0]); s0[1] = fmaf(x0, w.y, s0[1]);
      s0[2] = fmaf(x0, w.z, s0[2]); s0[3] = fmaf(x0, w.w, s0[3]);
      s1[0] = fmaf(x1, w.x, s1[0]); s1[1] = fmaf(x1, w.y, s1[1]);
      s1[2] = fmaf(x1, w.z, s1[2]); s1[3] = fmaf(x1, w.w, s1[3]);
    }
    float c = args.coef[l];
    float4 t0 = *(const float4*)&xs[grp][(half << 6) + (dt << 2)];
    float4 t1 = *(const float4*)&xs[grp + 16][(half << 6) + (dt << 2)];
    const float tv0[4] = {t0.x, t0.y, t0.z, t0.w};
    const float tv1[4] = {t1.x, t1.y, t1.z, t1.w};
#pragma unroll
    for (int ch = 0; ch < 4; ++ch) {
      osm_upd(m[0][ch], den[0][ch], num[0][ch], c * s0[ch] * am[ch], c * tv0[ch]);
      osm_upd(m[1][ch], den[1][ch], num[1][ch], c * s1[ch] * am[ch], c * tv1[ch]);
    }
  }
#pragma unroll
  for (int g = 0; g < 2; ++g) {
    int node = base + grp + g * 16;
    if (node >= n) continue;
    float4 o;
    o.x = num[g][0] / den[g][0];
    o.y = num[g][1] / den[g][1];
    o.z = num[g][2] / den[g][2];
    o.w = num[g][3] / den[g][3];
    size_t oi = (size_t)node * 32 + (half << 4) + dt;
    float4* op = (float4*)out + oi;
    if (beta) {
      float4 pv = *op;
      float4 ev = extra ? ((const float4*)extra)[oi] : make_float4(0.f, 0.f, 0.f, 0.f);
      o.x = pv.x + out_scale * o.x + escale * ev.x;
      o.y = pv.y + out_scale * o.y + escale * ev.y;
      o.z = pv.z + out_scale * o.z + escale * ev.z;
      o.w = pv.w + out_scale * o.w + escale * ev.w;
    } else {
      o.x *= out_scale; o.y *= out_scale; o.z *= out_scale; o.w *= out_scale;
    }
    *op = o;
  }
}

inline dim3 g1(long n) { return dim3((unsigned)((n + 255) / 256)); }

} // namespace

extern "C" void kernel_launch(void* const* d_in, const int* in_sizes, int n_in,
                              void* d_out, int out_size, void* d_ws, size_t ws_size,
                              hipStream_t stream) {
  const int* ug_u = (const int*)d_in[0];
  const int* ug_g = (const int*)d_in[1];
  const int* aS[3] = {(const int*)d_in[2], (const int*)d_in[4], (const int*)d_in[6]};
  const int* aD[3] = {(const int*)d_in[3], (const int*)d_in[5], (const int*)d_in[7]};
  const int* oS = (const int*)d_in[8];
  const int* oD = (const int*)d_in[9];
  const float* ue    = (const float*)d_in[10];
  const float* ie    = (const float*)d_in[11];
  const float* W_and = (const float*)d_in[12];
  const float* a_and = (const float*)d_in[13];
  const float* W_or  = (const float*)d_in[14];
  const float* a_or  = (const float*)d_in[15];
  const float* wedge = (const float*)d_in[16];
  const float* wnode = (const float*)d_in[17];

  // ---- workspace carve-up ----
  char* basep = (char*)d_ws;
  size_t boff_ = 0;
  auto alloc = [&](size_t bytes) -> void* {
    void* r = basep + boff_;
    boff_ += (bytes + 15) & ~(size_t)15;
    return r;
  };

  const int NCNT = NU + 9 * NI;
  int* cnt_all = (int*)alloc((size_t)NCNT * 4);
  float* inv_all = (float*)alloc((size_t)NCNT * 4);
  int* cU = cnt_all;
  int* cG = cU + NU;
  int* cAs[3], *cAd[3];
  { int* p = cG + NI;
    for (int i = 0; i < 3; ++i) { cAs[i] = p; p += NI; cAd[i] = p; p += NI; } }
  int* cOs = cAd[2] + NI;
  int* cOd = cOs + NI;
  float* invU = inv_all;
  float* invG = invU + NU;
  float* iAo[3], *iAi[3];
  { float* p = invG + NI;
    for (int i = 0; i < 3; ++i) { iAo[i] = p; p += NI; iAi[i] = p; p += NI; } }
  float* iOo = iAi[2] + NI;
  float* iOi = iOo + NI;

  int* oUGu = (int*)alloc((size_t)(NU + 1) * 4);
  int* oUGg = (int*)alloc((size_t)(NI + 1) * 4);
  int* oAnd[3]; for (int i = 0; i < 3; ++i) oAnd[i] = (int*)alloc((size_t)(NI + 1) * 4);
  int* oOr = (int*)alloc((size_t)(NI + 1) * 4);
  int* curUGu = (int*)alloc((size_t)(NU + 1) * 4);
  int* curUGg = (int*)alloc((size_t)(NI + 1) * 4);
  int* curAnd[3]; for (int i = 0; i < 3; ++i) curAnd[i] = (int*)alloc((size_t)(NI + 1) * 4);
  int* curOr = (int*)alloc((size_t)(NI + 1) * 4);

  int* sUGu = (int*)alloc((size_t)EUG * 4);
  float* wUGu = (float*)alloc((size_t)EUG * 4);
  int* sUGg = (int*)alloc((size_t)EUG * 4);
  int* sAnd[3]; for (int i = 0; i < 3; ++i) sAnd[i] = (int*)alloc((size_t)EAND * 4);
  int* sOr = (int*)alloc((size_t)EOR * 4);

  float* hu1 = (float*)alloc((size_t)NU * D * 4);
  float* hg1 = (float*)alloc((size_t)NI * D * 4);
  float* hg2 = (float*)alloc((size_t)NI * D * 4);
  float* ab[6]; for (int i = 0; i < 6; ++i) ab[i] = (float*)alloc((size_t)NI * D * 4);
  float* ob[3]; for (int i = 0; i < 3; ++i) ob[i] = (float*)alloc((size_t)NI * D * 4);

  float* out_hu = (float*)d_out;
  float* out_game = out_hu + (size_t)NU * D;

  // ---- degrees (fused) ----
  hipMemsetAsync(cnt_all, 0, (size_t)NCNT * 4, stream);
  CountAll C{};
  {
    const int* idxs[10] = {ug_u, ug_g, aS[0], aD[0], aS[1], aD[1], aS[2], aD[2], oS, oD};
    int* cnts[10] = {cU, cG, cAs[0], cAd[0], cAs[1], cAd[1], cAs[2], cAd[2], cOs, cOd};
    int ns[10] = {EUG, EUG, EAND, EAND, EAND, EAND, EAND, EAND, EOR, EOR};
    int bb = 0;
    for (int i = 0; i < 10; ++i) {
      C.idx[i] = idxs[i]; C.cnt[i] = cnts[i]; C.n[i] = ns[i];
      C.blkbase[i] = bb; bb += (ns[i] + 255) / 256;
    }
    C.blkbase[10] = bb;
  }
  count_all_k<<<dim3(C.blkbase[10]), 256, 0, stream>>>(C);
  norms_k<<<g1(NCNT), 256, 0, stream>>>(cnt_all, inv_all, NCNT);

  // ---- node-level scans (off + cur) ----
  ScanAll SA{};
  SA.s[0] = {cU, oUGu, curUGu, NU};
  SA.s[1] = {cG, oUGg, curUGg, NI};
  for (int i = 0; i < 3; ++i) SA.s[2 + i] = {cAd[i], oAnd[i], curAnd[i], NI};
  SA.s[5] = {cOd, oOr, curOr, NI};
  exscan_multi_k<<<dim3(6), 1024, 0, stream>>>(SA);

  // ---- windowed CSR fills: NPASS passes, each confined to 1/NPASS of dst range ----
  FillWin F{};
  {
    const int* ds[6] = {ug_u, ug_g, aD[0], aD[1], aD[2], oD};
    const int* ss[6] = {ug_g, ug_u, aS[0], aS[1], aS[2], oS};
    int* cs[6] = {curUGu, curUGg, curAnd[0], curAnd[1], curAnd[2], curOr};
    int* os[6] = {sUGu, sUGg, sAnd[0], sAnd[1], sAnd[2], sOr};
    int ns[6] = {EUG, EUG, EAND, EAND, EAND, EOR};
    int bb = 0;
    for (int i = 0; i < 6; ++i) {
      F.dst[i] = ds[i]; F.src[i] = ss[i]; F.cur[i] = cs[i]; F.csrc[i] = os[i]; F.n[i] = ns[i];
      F.blkbase[i] = bb; bb += (ns[i] + 255) / 256;
    }
    F.blkbase[6] = bb;
    F.cwt = wUGu; F.invS0 = invG; F.wn0 = wnode; F.we0 = wedge;
  }
  const int nodecount[6] = {NU, NI, NI, NI, NI, NI};
  for (int p = 0; p < NPASS; ++p) {
    for (int i = 0; i < 6; ++i) {
      int w = (nodecount[i] + NPASS - 1) / NPASS;
      F.wbeg[i] = p * w;
      F.wend[i] = min((p + 1) * w, nodecount[i]);
    }
    fill_win_k<<<dim3(F.blkbase[6]), 256, 0, stream>>>(F);
  }

  // ---- gathers (multi-job, 6 jobs per launch) ----
  auto launch_bg = [&](GJob* jobs, const int* rows, int nj) {
    GJobs J{};
    int tot = 0;
    for (int k = 0; k < nj; ++k) {
      J.j[k] = jobs[k];
      J.j[k].rbeg = tot;
      tot += rows[k];
    }
    for (int k = nj; k < 6; ++k) { J.j[k] = J.j[0]; J.j[k].rbeg = 0x7fffffff; }
    J.total = tot;
    gather_multi_k<<<dim3((tot + 3) / 4), 256, 0, stream>>>(J);
  };

  // G1: hu1<-ie (UGu), hg1<-ue (UGg), ab0..2<-ie (AND), ob0<-ie (OR)
  {
    GJob js[6] = {
      {ie, oUGu, sUGu, wUGu, nullptr, invU, hu1, 0},
      {ue, oUGg, sUGg, nullptr, invU, invG, hg1, 0},
      {ie, oAnd[0], sAnd[0], nullptr, iAo[0], iAi[0], ab[0], 0},
      {ie, oAnd[1], sAnd[1], nullptr, iAo[1], iAi[1], ab[1], 0},
      {ie, oAnd[2], sAnd[2], nullptr, iAo[2], iAi[2], ab[2], 0},
      {ie, oOr, sOr, nullptr, iOo, iOi, ob[0], 0},
    };
    const int rows[6] = {NU, NI, NI, NI, NI, NI};
    launch_bg(js, rows, 6);
  }
  // G2: out_hu<-hg1, hg2<-hu1, ab3..5<-ab0..2, ob1<-ob0
  {
    GJob js[6] = {
      {hg1, oUGu, sUGu, wUGu, nullptr, invU, out_hu, 0},
      {hu1, oUGg, sUGg, nullptr, invU, invG, hg2, 0},
      {ab[0], oAnd[0], sAnd[0], nullptr, iAo[0], iAi[0], ab[3], 0},
      {ab[1], oAnd[1], sAnd[1], nullptr, iAo[1], iAi[1], ab[4], 0},
      {ab[2], oAnd[2], sAnd[2], nullptr, iAo[2], iAi[2], ab[5], 0},
      {ob[0], oOr, sOr, nullptr, iOo, iOi, ob[1], 0},
    };
    const int rows[6] = {NU, NI, NI, NI, NI, NI};
    launch_bg(js, rows, 6);
  }
  // G3: ob2<-ob1
  {
    GJob js[1] = {{ob[1], oOr, sOr, nullptr, iOo, iOi, ob[2], 0}};
    const int rows[1] = {NI};
    launch_bg(js, rows, 1);
  }

  const float w_or = 80.0f / 82.0f;
  const float w_and = w_or / 80.0f;   // = 1/82
  const float w_self = w_and;

  // ---- layer attention ----
  AttnArgs aa{};
  aa.layer[0] = ie;
  for (int i = 0; i < 6; ++i) aa.layer[1 + i] = ab[i];
  for (int i = 0; i < 7; ++i) aa.coef[i] = 1.0f;
  attn_k<7><<<dim3((NI + 31) / 32, 2), 256, 0, stream>>>(
      aa, W_and, a_and, out_game, w_and, 0, nullptr, 0.f, NI);

  AttnArgs ao{};
  ao.layer[0] = ie; ao.layer[1] = ob[0]; ao.layer[2] = ob[1]; ao.layer[3] = ob[2];
  ao.coef[0] = 1.0f; ao.coef[1] = 0.6f; ao.coef[2] = 0.8f; ao.coef[3] = 1.0f;
  attn_k<4><<<dim3((NI + 31) / 32, 2), 256, 0, stream>>>(
      ao, W_or, a_or, out_game, w_or, 1, hg2, w_self, NI);
}

// Round 6
// 1908.736 us; speedup vs baseline: 7.4735x; 1.2297x over previous
//
#include <hip/hip_runtime.h>
#include <hip/hip_bf16.h>
#include <math.h>

namespace {

constexpr int NU   = 50000;
constexpr int NI   = 30000;
constexpr int D    = 128;
constexpr int EUG  = 2000000;
constexpr int EAND = 1000000;
constexpr int EOR  = 1000000;
constexpr int NPASS = 3;   // windowed fill passes

typedef unsigned short ushort_t;

// ---- bf16 helpers (tables stored as uint = 2x bf16; lane covers ch 2l, 2l+1) ----
__device__ inline float bf_lo(unsigned v) { union { unsigned u; float f; } x{v << 16}; return x.f; }
__device__ inline float bf_hi(unsigned v) { union { unsigned u; float f; } x{v & 0xffff0000u}; return x.f; }
__device__ inline unsigned short f2bf(float f) {
  union { float f; unsigned u; } x{f};
  unsigned r = x.u + 0x7fffu + ((x.u >> 16) & 1u);
  return (unsigned short)(r >> 16);
}
__device__ inline unsigned pack2bf(float a, float b) {
  return (unsigned)f2bf(a) | ((unsigned)f2bf(b) << 16);
}

// ---------- fp32 -> bf16 table conversion (ie + ue fused) ----------
__global__ void cvt_bf16_k(const float* __restrict__ a, unsigned* __restrict__ ah, long n2a,
                           const float* __restrict__ b, unsigned* __restrict__ bh, long n2b) {
  long t = (long)blockIdx.x * 256 + threadIdx.x;
  if (t < n2a) {
    float2 v = ((const float2*)a)[t];
    ah[t] = pack2bf(v.x, v.y);
  } else if (t < n2a + n2b) {
    long u = t - n2a;
    float2 v = ((const float2*)b)[u];
    bh[u] = pack2bf(v.x, v.y);
  }
}

// ---------- fused degree counts ----------
struct CountAll {
  const int* idx[10];
  int* cnt[10];
  int n[10];
  int blkbase[11];
};
__global__ __launch_bounds__(256) void count_all_k(CountAll C) {
  int seg = 0;
#pragma unroll
  for (int i = 1; i < 10; ++i) if ((int)blockIdx.x >= C.blkbase[i]) seg = i;
  int t = ((int)blockIdx.x - C.blkbase[seg]) * 256 + (int)threadIdx.x;
  if (t < C.n[seg]) atomicAdd(&C.cnt[seg][C.idx[seg][t]], 1);
}

__global__ void norms_k(const int* __restrict__ cnt, float* __restrict__ inv, int n) {
  int t = blockIdx.x * 256 + threadIdx.x;
  if (t < n) inv[t] = rsqrtf((float)max(cnt[t], 1));
}

// ---------- fused exclusive scans (one workgroup per segment) ----------
struct ScanSeg { const int* cnt; int* off; int* cur; int n; };
struct ScanAll { ScanSeg s[6]; };
__global__ __launch_bounds__(1024) void exscan_multi_k(ScanAll S) {
  ScanSeg sg = S.s[blockIdx.x];
  __shared__ int ts[1024];
  const int t = threadIdx.x;
  const int per = (sg.n + 1023) >> 10;
  const int b = min(t * per, sg.n);
  const int e = min(b + per, sg.n);
  int s = 0;
  for (int i = b; i < e; ++i) s += sg.cnt[i];
  ts[t] = s;
  __syncthreads();
  for (int d = 1; d < 1024; d <<= 1) {
    int v = (t >= d) ? ts[t - d] : 0;
    __syncthreads();
    ts[t] += v;
    __syncthreads();
  }
  if (t == 1023) sg.off[sg.n] = ts[1023];
  int run = (t == 0) ? 0 : ts[t - 1];
  for (int i = b; i < e; ++i) { sg.off[i] = run; sg.cur[i] = run; run += sg.cnt[i]; }
}

// ---------- windowed CSR fill (pass p only handles dst in [wbeg,wend)) ----------
struct FillWin {
  const int* dst[6];
  const int* src[6];
  int* cur[6];
  ushort_t* csrc[6];
  float* cwt;           // segment 0 only (UG user side)
  const float* invS0;   // invG
  const float* wn0;
  const float* we0;
  int n[6];
  int wbeg[6];
  int wend[6];
  int blkbase[7];
};
__global__ __launch_bounds__(256) void fill_win_k(FillWin F) {
  int seg = 0;
#pragma unroll
  for (int i = 1; i < 6; ++i) if ((int)blockIdx.x >= F.blkbase[i]) seg = i;
  int e = ((int)blockIdx.x - F.blkbase[seg]) * 256 + (int)threadIdx.x;
  if (e >= F.n[seg]) return;
  int dn = F.dst[seg][e];
  if (dn < F.wbeg[seg] || dn >= F.wend[seg]) return;
  int sn = F.src[seg][e];
  int pos = atomicAdd(&F.cur[seg][dn], 1);
  F.csrc[seg][pos] = (ushort_t)sn;
  if (seg == 0) F.cwt[pos] = F.invS0[sn] * F.wn0[sn] * F.we0[e];
}

// ---------- multi-job pull aggregation: one 64-lane wave per dst row ----------
// x tables are bf16 (uint = 2 ch); output bf16 (out_h) or fp32 (out_f).
struct GJob {
  const unsigned* x; const int* roff; const ushort_t* csrc; const float* cwt;
  const float* invS; const float* invD; unsigned* out_h; float* out_f; int rbeg;
};
struct GJobs { GJob j[6]; int total; };

__global__ __launch_bounds__(256) void gather_multi_k(GJobs J) {
  int wid = ((int)blockIdx.x << 2) | ((int)threadIdx.x >> 6);
  if (wid >= J.total) return;
  GJob jb = J.j[0];
#pragma unroll
  for (int i = 1; i < 6; ++i) if (wid >= J.j[i].rbeg) jb = J.j[i];
  int row = wid - jb.rbeg;
  int lane = (int)threadIdx.x & 63;
  int beg = __builtin_amdgcn_readfirstlane(jb.roff[row]);
  int end = __builtin_amdgcn_readfirstlane(jb.roff[row + 1]);
  const unsigned* __restrict__ x = jb.x;
  const ushort_t* __restrict__ cs = jb.csrc;
  float ax = 0.f, ay = 0.f;
  int j = beg;
  if (jb.cwt) {
    const float* __restrict__ cw = jb.cwt;
    for (; j + 7 < end; j += 8) {
      int s[8]; float w[8];
#pragma unroll
      for (int k = 0; k < 8; ++k) { s[k] = cs[j + k]; w[k] = cw[j + k]; }
#pragma unroll
      for (int k = 0; k < 8; ++k) {
        unsigned v = x[(size_t)s[k] * 64 + lane];
        ax = fmaf(w[k], bf_lo(v), ax); ay = fmaf(w[k], bf_hi(v), ay);
      }
    }
    for (; j + 3 < end; j += 4) {
      int s[4]; float w[4];
#pragma unroll
      for (int k = 0; k < 4; ++k) { s[k] = cs[j + k]; w[k] = cw[j + k]; }
#pragma unroll
      for (int k = 0; k < 4; ++k) {
        unsigned v = x[(size_t)s[k] * 64 + lane];
        ax = fmaf(w[k], bf_lo(v), ax); ay = fmaf(w[k], bf_hi(v), ay);
      }
    }
    for (; j < end; ++j) {
      int s = cs[j]; float w = cw[j];
      unsigned v = x[(size_t)s * 64 + lane];
      ax = fmaf(w, bf_lo(v), ax); ay = fmaf(w, bf_hi(v), ay);
    }
  } else {
    const float* __restrict__ is = jb.invS;
    for (; j + 7 < end; j += 8) {
      int s[8]; float w[8];
#pragma unroll
      for (int k = 0; k < 8; ++k) { s[k] = cs[j + k]; w[k] = is[s[k]]; }
#pragma unroll
      for (int k = 0; k < 8; ++k) {
        unsigned v = x[(size_t)s[k] * 64 + lane];
        ax = fmaf(w[k], bf_lo(v), ax); ay = fmaf(w[k], bf_hi(v), ay);
      }
    }
    for (; j + 3 < end; j += 4) {
      int s[4]; float w[4];
#pragma unroll
      for (int k = 0; k < 4; ++k) { s[k] = cs[j + k]; w[k] = is[s[k]]; }
#pragma unroll
      for (int k = 0; k < 4; ++k) {
        unsigned v = x[(size_t)s[k] * 64 + lane];
        ax = fmaf(w[k], bf_lo(v), ax); ay = fmaf(w[k], bf_hi(v), ay);
      }
    }
    for (; j < end; ++j) {
      int s = cs[j]; float w = is[s];
      unsigned v = x[(size_t)s * 64 + lane];
      ax = fmaf(w, bf_lo(v), ax); ay = fmaf(w, bf_hi(v), ay);
    }
  }
  float si = jb.invD[row];
  ax *= si; ay *= si;
  if (jb.out_f) {
    float2 o; o.x = ax; o.y = ay;
    ((float2*)jb.out_f)[(size_t)row * 64 + lane] = o;
  } else {
    jb.out_h[(size_t)row * 64 + lane] = pack2bf(ax, ay);
  }
}

// ---------- layer attention: bf16 layers, fp32 math, fp32 out ----------
struct AttnArgs {
  const unsigned* layer[7];
  float coef[7];
};

__device__ inline void osm_upd(float& m, float& den, float& num, float sc, float tv) {
  float nm = fmaxf(m, sc);
  float e0 = __expf(m - nm);
  float e1 = __expf(sc - nm);
  den = den * e0 + e1;
  num = num * e0 + tv * e1;
  m = nm;
}

template <int L>
__global__ __launch_bounds__(256) void attn_k(AttnArgs args,
    const float* __restrict__ W, const float* __restrict__ avec,
    float* __restrict__ out, float out_scale, int beta,
    const unsigned* __restrict__ extra, float escale, int n) {
  __shared__ float4 Ws4[2048];
  __shared__ float xs[32][132];
  const int tid = threadIdx.x;
  const int dt = tid & 15;
  const int grp = tid >> 4;
  const int half = blockIdx.y;
  const int base = blockIdx.x * 32;
  const float4* __restrict__ W4 = (const float4*)W;

  for (int i = tid; i < 2048; i += 256) {
    int k = i >> 4, d = i & 15;
    Ws4[i] = W4[(k << 5) + (half << 4) + d];
  }
  const float4 a4 = ((const float4*)avec)[(half << 4) + dt];
  const float am[4] = {a4.x, a4.y, a4.z, a4.w};

  float m[2][4], den[2][4], num[2][4];
#pragma unroll
  for (int g = 0; g < 2; ++g)
#pragma unroll
    for (int c = 0; c < 4; ++c) { m[g][c] = -3.0e38f; den[g][c] = 0.f; num[g][c] = 0.f; }

#pragma unroll
  for (int l = 0; l < L; ++l) {
    __syncthreads();
    const unsigned* __restrict__ Lh = args.layer[l];
    for (int i = tid; i < 2048; i += 256) {
      int r = i >> 6, c2 = i & 63;
      int node = base + r;
      unsigned v = (node < n) ? Lh[(size_t)node * 64 + c2] : 0u;
      xs[r][(c2 << 1)] = bf_lo(v);
      xs[r][(c2 << 1) + 1] = bf_hi(v);
    }
    __syncthreads();
    float s0[4] = {0.f, 0.f, 0.f, 0.f}, s1[4] = {0.f, 0.f, 0.f, 0.f};
#pragma unroll 4
    for (int k = 0; k < 128; ++k) {
      float4 w = Ws4[(k << 4) + dt];
      float x0 = xs[grp][k];
      float x1 = xs[grp + 16][k];
      s0[0] = fmaf(x0, w.x, s0[0]); s0[1] = fmaf(x0, w.y, s0[1]);
      s0[2] = fmaf(x0, w.z, s0[2]); s0[3] = fmaf(x0, w.w, s0[3]);
      s1[0] = fmaf(x1, w.x, s1[0]); s1[1] = fmaf(x1, w.y, s1[1]);
      s1[2] = fmaf(x1, w.z, s1[2]); s1[3] = fmaf(x1, w.w, s1[3]);
    }
    float c = args.coef[l];
    float4 t0 = *(const float4*)&xs[grp][(half << 6) + (dt << 2)];
    float4 t1 = *(const float4*)&xs[grp + 16][(half << 6) + (dt << 2)];
    const float tv0[4] = {t0.x, t0.y, t0.z, t0.w};
    const float tv1[4] = {t1.x, t1.y, t1.z, t1.w};
#pragma unroll
    for (int ch = 0; ch < 4; ++ch) {
      osm_upd(m[0][ch], den[0][ch], num[0][ch], c * s0[ch] * am[ch], c * tv0[ch]);
      osm_upd(m[1][ch], den[1][ch], num[1][ch], c * s1[ch] * am[ch], c * tv1[ch]);
    }
  }
#pragma unroll
  for (int g = 0; g < 2; ++g) {
    int node = base + grp + g * 16;
    if (node >= n) continue;
    float4 o;
    o.x = num[g][0] / den[g][0];
    o.y = num[g][1] / den[g][1];
    o.z = num[g][2] / den[g][2];
    o.w = num[g][3] / den[g][3];
    size_t oi = (size_t)node * 32 + (half << 4) + dt;
    float4* op = (float4*)out + oi;
    if (beta) {
      float4 pv = *op;
      float ex = 0.f, ey = 0.f, ez = 0.f, ew = 0.f;
      if (extra) {
        uint2 ev = ((const uint2*)extra)[oi];
        ex = bf_lo(ev.x); ey = bf_hi(ev.x); ez = bf_lo(ev.y); ew = bf_hi(ev.y);
      }
      o.x = pv.x + out_scale * o.x + escale * ex;
      o.y = pv.y + out_scale * o.y + escale * ey;
      o.z = pv.z + out_scale * o.z + escale * ez;
      o.w = pv.w + out_scale * o.w + escale * ew;
    } else {
      o.x *= out_scale; o.y *= out_scale; o.z *= out_scale; o.w *= out_scale;
    }
    *op = o;
  }
}

inline dim3 g1(long n) { return dim3((unsigned)((n + 255) / 256)); }

} // namespace

extern "C" void kernel_launch(void* const* d_in, const int* in_sizes, int n_in,
                              void* d_out, int out_size, void* d_ws, size_t ws_size,
                              hipStream_t stream) {
  const int* ug_u = (const int*)d_in[0];
  const int* ug_g = (const int*)d_in[1];
  const int* aS[3] = {(const int*)d_in[2], (const int*)d_in[4], (const int*)d_in[6]};
  const int* aD[3] = {(const int*)d_in[3], (const int*)d_in[5], (const int*)d_in[7]};
  const int* oS = (const int*)d_in[8];
  const int* oD = (const int*)d_in[9];
  const float* ue    = (const float*)d_in[10];
  const float* ie    = (const float*)d_in[11];
  const float* W_and = (const float*)d_in[12];
  const float* a_and = (const float*)d_in[13];
  const float* W_or  = (const float*)d_in[14];
  const float* a_or  = (const float*)d_in[15];
  const float* wedge = (const float*)d_in[16];
  const float* wnode = (const float*)d_in[17];

  // ---- workspace carve-up ----
  char* basep = (char*)d_ws;
  size_t boff_ = 0;
  auto alloc = [&](size_t bytes) -> void* {
    void* r = basep + boff_;
    boff_ += (bytes + 15) & ~(size_t)15;
    return r;
  };

  const int NCNT = NU + 9 * NI;
  int* cnt_all = (int*)alloc((size_t)NCNT * 4);
  float* inv_all = (float*)alloc((size_t)NCNT * 4);
  int* cU = cnt_all;
  int* cG = cU + NU;
  int* cAs[3], *cAd[3];
  { int* p = cG + NI;
    for (int i = 0; i < 3; ++i) { cAs[i] = p; p += NI; cAd[i] = p; p += NI; } }
  int* cOs = cAd[2] + NI;
  int* cOd = cOs + NI;
  float* invU = inv_all;
  float* invG = invU + NU;
  float* iAo[3], *iAi[3];
  { float* p = invG + NI;
    for (int i = 0; i < 3; ++i) { iAo[i] = p; p += NI; iAi[i] = p; p += NI; } }
  float* iOo = iAi[2] + NI;
  float* iOi = iOo + NI;

  int* oUGu = (int*)alloc((size_t)(NU + 1) * 4);
  int* oUGg = (int*)alloc((size_t)(NI + 1) * 4);
  int* oAnd[3]; for (int i = 0; i < 3; ++i) oAnd[i] = (int*)alloc((size_t)(NI + 1) * 4);
  int* oOr = (int*)alloc((size_t)(NI + 1) * 4);
  int* curUGu = (int*)alloc((size_t)(NU + 1) * 4);
  int* curUGg = (int*)alloc((size_t)(NI + 1) * 4);
  int* curAnd[3]; for (int i = 0; i < 3; ++i) curAnd[i] = (int*)alloc((size_t)(NI + 1) * 4);
  int* curOr = (int*)alloc((size_t)(NI + 1) * 4);

  ushort_t* sUGu = (ushort_t*)alloc((size_t)EUG * 2);
  float* wUGu = (float*)alloc((size_t)EUG * 4);
  ushort_t* sUGg = (ushort_t*)alloc((size_t)EUG * 2);
  ushort_t* sAnd[3]; for (int i = 0; i < 3; ++i) sAnd[i] = (ushort_t*)alloc((size_t)EAND * 2);
  ushort_t* sOr = (ushort_t*)alloc((size_t)EOR * 2);

  // bf16 tables (row = 64 uints = 256 B)
  unsigned* ieh = (unsigned*)alloc((size_t)NI * 64 * 4);
  unsigned* ueh = (unsigned*)alloc((size_t)NU * 64 * 4);
  unsigned* hu1 = (unsigned*)alloc((size_t)NU * 64 * 4);
  unsigned* hg1 = (unsigned*)alloc((size_t)NI * 64 * 4);
  unsigned* hg2 = (unsigned*)alloc((size_t)NI * 64 * 4);
  unsigned* ab[6]; for (int i = 0; i < 6; ++i) ab[i] = (unsigned*)alloc((size_t)NI * 64 * 4);
  unsigned* ob[3]; for (int i = 0; i < 3; ++i) ob[i] = (unsigned*)alloc((size_t)NI * 64 * 4);

  float* out_hu = (float*)d_out;
  float* out_game = out_hu + (size_t)NU * D;

  // ---- bf16 conversion of input embeddings ----
  {
    long n2a = (long)NI * 64, n2b = (long)NU * 64;
    cvt_bf16_k<<<g1(n2a + n2b), 256, 0, stream>>>(ie, ieh, n2a, ue, ueh, n2b);
  }

  // ---- degrees (fused) ----
  hipMemsetAsync(cnt_all, 0, (size_t)NCNT * 4, stream);
  CountAll C{};
  {
    const int* idxs[10] = {ug_u, ug_g, aS[0], aD[0], aS[1], aD[1], aS[2], aD[2], oS, oD};
    int* cnts[10] = {cU, cG, cAs[0], cAd[0], cAs[1], cAd[1], cAs[2], cAd[2], cOs, cOd};
    int ns[10] = {EUG, EUG, EAND, EAND, EAND, EAND, EAND, EAND, EOR, EOR};
    int bb = 0;
    for (int i = 0; i < 10; ++i) {
      C.idx[i] = idxs[i]; C.cnt[i] = cnts[i]; C.n[i] = ns[i];
      C.blkbase[i] = bb; bb += (ns[i] + 255) / 256;
    }
    C.blkbase[10] = bb;
  }
  count_all_k<<<dim3(C.blkbase[10]), 256, 0, stream>>>(C);
  norms_k<<<g1(NCNT), 256, 0, stream>>>(cnt_all, inv_all, NCNT);

  // ---- node-level scans (off + cur) ----
  ScanAll SA{};
  SA.s[0] = {cU, oUGu, curUGu, NU};
  SA.s[1] = {cG, oUGg, curUGg, NI};
  for (int i = 0; i < 3; ++i) SA.s[2 + i] = {cAd[i], oAnd[i], curAnd[i], NI};
  SA.s[5] = {cOd, oOr, curOr, NI};
  exscan_multi_k<<<dim3(6), 1024, 0, stream>>>(SA);

  // ---- windowed CSR fills ----
  FillWin F{};
  {
    const int* ds[6] = {ug_u, ug_g, aD[0], aD[1], aD[2], oD};
    const int* ss[6] = {ug_g, ug_u, aS[0], aS[1], aS[2], oS};
    int* cs[6] = {curUGu, curUGg, curAnd[0], curAnd[1], curAnd[2], curOr};
    ushort_t* os[6] = {sUGu, sUGg, sAnd[0], sAnd[1], sAnd[2], sOr};
    int ns[6] = {EUG, EUG, EAND, EAND, EAND, EOR};
    int bb = 0;
    for (int i = 0; i < 6; ++i) {
      F.dst[i] = ds[i]; F.src[i] = ss[i]; F.cur[i] = cs[i]; F.csrc[i] = os[i]; F.n[i] = ns[i];
      F.blkbase[i] = bb; bb += (ns[i] + 255) / 256;
    }
    F.blkbase[6] = bb;
    F.cwt = wUGu; F.invS0 = invG; F.wn0 = wnode; F.we0 = wedge;
  }
  const int nodecount[6] = {NU, NI, NI, NI, NI, NI};
  for (int p = 0; p < NPASS; ++p) {
    for (int i = 0; i < 6; ++i) {
      int w = (nodecount[i] + NPASS - 1) / NPASS;
      F.wbeg[i] = p * w;
      F.wend[i] = min((p + 1) * w, nodecount[i]);
    }
    fill_win_k<<<dim3(F.blkbase[6]), 256, 0, stream>>>(F);
  }

  // ---- gathers (multi-job, 6 jobs per launch) ----
  auto launch_bg = [&](GJob* jobs, const int* rows, int nj) {
    GJobs J{};
    int tot = 0;
    for (int k = 0; k < nj; ++k) {
      J.j[k] = jobs[k];
      J.j[k].rbeg = tot;
      tot += rows[k];
    }
    for (int k = nj; k < 6; ++k) { J.j[k] = J.j[0]; J.j[k].rbeg = 0x7fffffff; }
    J.total = tot;
    gather_multi_k<<<dim3((tot + 3) / 4), 256, 0, stream>>>(J);
  };

  // G1: hu1<-ieh (UGu), hg1<-ueh (UGg), ab0..2<-ieh (AND), ob0<-ieh (OR)
  {
    GJob js[6] = {
      {ieh, oUGu, sUGu, wUGu, nullptr, invU, hu1, nullptr, 0},
      {ueh, oUGg, sUGg, nullptr, invU, invG, hg1, nullptr, 0},
      {ieh, oAnd[0], sAnd[0], nullptr, iAo[0], iAi[0], ab[0], nullptr, 0},
      {ieh, oAnd[1], sAnd[1], nullptr, iAo[1], iAi[1], ab[1], nullptr, 0},
      {ieh, oAnd[2], sAnd[2], nullptr, iAo[2], iAi[2], ab[2], nullptr, 0},
      {ieh, oOr, sOr, nullptr, iOo, iOi, ob[0], nullptr, 0},
    };
    const int rows[6] = {NU, NI, NI, NI, NI, NI};
    launch_bg(js, rows, 6);
  }
  // G2: out_hu<-hg1 (fp32 out), hg2<-hu1, ab3..5<-ab0..2, ob1<-ob0
  {
    GJob js[6] = {
      {hg1, oUGu, sUGu, wUGu, nullptr, invU, nullptr, out_hu, 0},
      {hu1, oUGg, sUGg, nullptr, invU, invG, hg2, nullptr, 0},
      {ab[0], oAnd[0], sAnd[0], nullptr, iAo[0], iAi[0], ab[3], nullptr, 0},
      {ab[1], oAnd[1], sAnd[1], nullptr, iAo[1], iAi[1], ab[4], nullptr, 0},
      {ab[2], oAnd[2], sAnd[2], nullptr, iAo[2], iAi[2], ab[5], nullptr, 0},
      {ob[0], oOr, sOr, nullptr, iOo, iOi, ob[1], nullptr, 0},
    };
    const int rows[6] = {NU, NI, NI, NI, NI, NI};
    launch_bg(js, rows, 6);
  }
  // G3: ob2<-ob1
  {
    GJob js[1] = {{ob[1], oOr, sOr, nullptr, iOo, iOi, ob[2], nullptr, 0}};
    const int rows[1] = {NI};
    launch_bg(js, rows, 1);
  }

  const float w_or = 80.0f / 82.0f;
  const float w_and = w_or / 80.0f;   // = 1/82
  const float w_self = w_and;

  // ---- layer attention ----
  AttnArgs aa{};
  aa.layer[0] = ieh;
  for (int i = 0; i < 6; ++i) aa.layer[1 + i] = ab[i];
  for (int i = 0; i < 7; ++i) aa.coef[i] = 1.0f;
  attn_k<7><<<dim3((NI + 31) / 32, 2), 256, 0, stream>>>(
      aa, W_and, a_and, out_game, w_and, 0, nullptr, 0.f, NI);

  AttnArgs ao{};
  ao.layer[0] = ieh; ao.layer[1] = ob[0]; ao.layer[2] = ob[1]; ao.layer[3] = ob[2];
  ao.coef[0] = 1.0f; ao.coef[1] = 0.6f; ao.coef[2] = 0.8f; ao.coef[3] = 1.0f;
  attn_k<4><<<dim3((NI + 31) / 32, 2), 256, 0, stream>>>(
      ao, W_or, a_or, out_game, w_or, 1, hg2, w_self, NI);
}

// Round 7
// 1519.315 us; speedup vs baseline: 9.3890x; 1.2563x over previous
//
#include <hip/hip_runtime.h>
#include <hip/hip_bf16.h>
#include <math.h>

namespace {

constexpr int NU   = 50000;
constexpr int NI   = 30000;
constexpr int D    = 128;
constexpr int EUG  = 2000000;
constexpr int EAND = 1000000;
constexpr int EOR  = 1000000;
constexpr int NPASS = 3;     // windowed fill passes
constexpr int HNB  = 8;      // histo blocks per (array,window) unit
constexpr int HW   = 16000;  // max histogram window (64 KB LDS)

typedef unsigned short ushort_t;

// ---- bf16 helpers (tables stored as uint = 2x bf16; lane covers ch 2l, 2l+1) ----
__device__ inline float bf_lo(unsigned v) { union { unsigned u; float f; } x{v << 16}; return x.f; }
__device__ inline float bf_hi(unsigned v) { union { unsigned u; float f; } x{v & 0xffff0000u}; return x.f; }
__device__ inline unsigned short f2bf(float f) {
  union { float f; unsigned u; } x{f};
  unsigned r = x.u + 0x7fffu + ((x.u >> 16) & 1u);
  return (unsigned short)(r >> 16);
}
__device__ inline unsigned pack2bf(float a, float b) {
  return (unsigned)f2bf(a) | ((unsigned)f2bf(b) << 16);
}

// ---------- fused: LDS-window histograms (176 blocks) + bf16 cvt (rest) ----------
struct HistoUnit { const int* idx; int* cnt; int E; int wbeg; int wend; };
struct HistoAll {
  HistoUnit u[22];
  int blkbase[23];
  int nunits;
  int nhisto;       // total histo blocks
  const float* a; unsigned* ah; long n2a;   // ie -> ieh
  const float* b; unsigned* bh; long n2b;   // ue -> ueh
};
__global__ __launch_bounds__(1024) void histo_cvt_k(HistoAll H) {
  __shared__ int h[HW];
  int gb = (int)blockIdx.x;
  if (gb >= H.nhisto) {
    long nb = (long)gridDim.x - H.nhisto;
    long total = H.n2a + H.n2b;
    for (long t = (long)(gb - H.nhisto) * 1024 + threadIdx.x; t < total; t += nb * 1024) {
      if (t < H.n2a) {
        float2 v = ((const float2*)H.a)[t];
        H.ah[t] = pack2bf(v.x, v.y);
      } else {
        long u = t - H.n2a;
        float2 v = ((const float2*)H.b)[u];
        H.bh[u] = pack2bf(v.x, v.y);
      }
    }
    return;
  }
  int unit = 0;
#pragma unroll
  for (int i = 1; i < 22; ++i) if (i < H.nunits && gb >= H.blkbase[i]) unit = i;
  HistoUnit U = H.u[unit];
  const int W = U.wend - U.wbeg;
  for (int i = threadIdx.x; i < W; i += 1024) h[i] = 0;
  __syncthreads();
  int chunk = gb - H.blkbase[unit];
  long b = (long)U.E * chunk / HNB;
  long e = (long)U.E * (chunk + 1) / HNB;
  const int* __restrict__ idx = U.idx;
  for (long j = b + threadIdx.x; j < e; j += 1024) {
    int v = idx[j] - U.wbeg;
    if ((unsigned)v < (unsigned)W) atomicAdd(&h[v], 1);
  }
  __syncthreads();
  for (int i = threadIdx.x; i < W; i += 1024) {
    int v = h[i];
    if (v) atomicAdd(&U.cnt[U.wbeg + i], v);
  }
}

// ---------- fused exclusive scans (blocks 0-5) + rsqrt norms (blocks 6+) ----------
struct ScanSeg { const int* cnt; int* off; int* cur; int n; };
struct ScanAll {
  ScanSeg s[6];
  const int* cnt_all; float* inv_all; int ncnt;
};
__global__ __launch_bounds__(1024) void exscan_norms_k(ScanAll S) {
  if (blockIdx.x >= 6) {
    int t = ((int)blockIdx.x - 6) * 1024 + threadIdx.x;
    if (t < S.ncnt) S.inv_all[t] = rsqrtf((float)max(S.cnt_all[t], 1));
    return;
  }
  ScanSeg sg = S.s[blockIdx.x];
  __shared__ int ts[1024];
  const int t = threadIdx.x;
  const int per = (sg.n + 1023) >> 10;
  const int b = min(t * per, sg.n);
  const int e = min(b + per, sg.n);
  int s = 0;
  for (int i = b; i < e; ++i) s += sg.cnt[i];
  ts[t] = s;
  __syncthreads();
  for (int d = 1; d < 1024; d <<= 1) {
    int v = (t >= d) ? ts[t - d] : 0;
    __syncthreads();
    ts[t] += v;
    __syncthreads();
  }
  if (t == 1023) sg.off[sg.n] = ts[1023];
  int run = (t == 0) ? 0 : ts[t - 1];
  for (int i = b; i < e; ++i) { sg.off[i] = run; sg.cur[i] = run; run += sg.cnt[i]; }
}

// ---------- windowed CSR fill (pass p only handles dst in [wbeg,wend)) ----------
struct FillWin {
  const int* dst[6];
  const int* src[6];
  int* cur[6];
  ushort_t* csrc[6];
  float* cwt;           // segment 0 only (UG user side)
  const float* invS0;   // invG
  const float* wn0;
  const float* we0;
  int n[6];
  int wbeg[6];
  int wend[6];
  int blkbase[7];
};
__global__ __launch_bounds__(256) void fill_win_k(FillWin F) {
  int seg = 0;
#pragma unroll
  for (int i = 1; i < 6; ++i) if ((int)blockIdx.x >= F.blkbase[i]) seg = i;
  int e = ((int)blockIdx.x - F.blkbase[seg]) * 256 + (int)threadIdx.x;
  if (e >= F.n[seg]) return;
  int dn = F.dst[seg][e];
  if (dn < F.wbeg[seg] || dn >= F.wend[seg]) return;
  int sn = F.src[seg][e];
  int pos = atomicAdd(&F.cur[seg][dn], 1);
  F.csrc[seg][pos] = (ushort_t)sn;
  if (seg == 0) F.cwt[pos] = F.invS0[sn] * F.wn0[sn] * F.we0[e];
}

// ---------- multi-job pull aggregation: one 64-lane wave per dst row ----------
struct GJob {
  const unsigned* x; const int* roff; const ushort_t* csrc; const float* cwt;
  const float* invS; const float* invD; unsigned* out_h; float* out_f; int rbeg;
};
struct GJobs { GJob j[6]; int total; };

__global__ __launch_bounds__(256) void gather_multi_k(GJobs J) {
  int wid = ((int)blockIdx.x << 2) | ((int)threadIdx.x >> 6);
  if (wid >= J.total) return;
  GJob jb = J.j[0];
#pragma unroll
  for (int i = 1; i < 6; ++i) if (wid >= J.j[i].rbeg) jb = J.j[i];
  int row = wid - jb.rbeg;
  int lane = (int)threadIdx.x & 63;
  int beg = __builtin_amdgcn_readfirstlane(jb.roff[row]);
  int end = __builtin_amdgcn_readfirstlane(jb.roff[row + 1]);
  const unsigned* __restrict__ x = jb.x;
  const ushort_t* __restrict__ cs = jb.csrc;
  float ax = 0.f, ay = 0.f;
  int j = beg;
  if (jb.cwt) {
    const float* __restrict__ cw = jb.cwt;
    for (; j + 7 < end; j += 8) {
      int s[8]; float w[8];
#pragma unroll
      for (int k = 0; k < 8; ++k) { s[k] = cs[j + k]; w[k] = cw[j + k]; }
#pragma unroll
      for (int k = 0; k < 8; ++k) {
        unsigned v = x[(size_t)s[k] * 64 + lane];
        ax = fmaf(w[k], bf_lo(v), ax); ay = fmaf(w[k], bf_hi(v), ay);
      }
    }
    for (; j + 3 < end; j += 4) {
      int s[4]; float w[4];
#pragma unroll
      for (int k = 0; k < 4; ++k) { s[k] = cs[j + k]; w[k] = cw[j + k]; }
#pragma unroll
      for (int k = 0; k < 4; ++k) {
        unsigned v = x[(size_t)s[k] * 64 + lane];
        ax = fmaf(w[k], bf_lo(v), ax); ay = fmaf(w[k], bf_hi(v), ay);
      }
    }
    for (; j < end; ++j) {
      int s = cs[j]; float w = cw[j];
      unsigned v = x[(size_t)s * 64 + lane];
      ax = fmaf(w, bf_lo(v), ax); ay = fmaf(w, bf_hi(v), ay);
    }
  } else {
    const float* __restrict__ is = jb.invS;
    for (; j + 7 < end; j += 8) {
      int s[8]; float w[8];
#pragma unroll
      for (int k = 0; k < 8; ++k) { s[k] = cs[j + k]; w[k] = is[s[k]]; }
#pragma unroll
      for (int k = 0; k < 8; ++k) {
        unsigned v = x[(size_t)s[k] * 64 + lane];
        ax = fmaf(w[k], bf_lo(v), ax); ay = fmaf(w[k], bf_hi(v), ay);
      }
    }
    for (; j + 3 < end; j += 4) {
      int s[4]; float w[4];
#pragma unroll
      for (int k = 0; k < 4; ++k) { s[k] = cs[j + k]; w[k] = is[s[k]]; }
#pragma unroll
      for (int k = 0; k < 4; ++k) {
        unsigned v = x[(size_t)s[k] * 64 + lane];
        ax = fmaf(w[k], bf_lo(v), ax); ay = fmaf(w[k], bf_hi(v), ay);
      }
    }
    for (; j < end; ++j) {
      int s = cs[j]; float w = is[s];
      unsigned v = x[(size_t)s * 64 + lane];
      ax = fmaf(w, bf_lo(v), ax); ay = fmaf(w, bf_hi(v), ay);
    }
  }
  float si = jb.invD[row];
  ax *= si; ay *= si;
  if (jb.out_f) {
    float2 o; o.x = ax; o.y = ay;
    ((float2*)jb.out_f)[(size_t)row * 64 + lane] = o;
  } else {
    jb.out_h[(size_t)row * 64 + lane] = pack2bf(ax, ay);
  }
}

// ---------- layer attention: bf16 layers, fp32 math, fp32 out ----------
struct AttnArgs {
  const unsigned* layer[7];
  float coef[7];
};

__device__ inline void osm_upd(float& m, float& den, float& num, float sc, float tv) {
  float nm = fmaxf(m, sc);
  float e0 = __expf(m - nm);
  float e1 = __expf(sc - nm);
  den = den * e0 + e1;
  num = num * e0 + tv * e1;
  m = nm;
}

template <int L>
__global__ __launch_bounds__(256) void attn_k(AttnArgs args,
    const float* __restrict__ W, const float* __restrict__ avec,
    float* __restrict__ out, float out_scale, int beta,
    const unsigned* __restrict__ extra, float escale, int n) {
  __shared__ float4 Ws4[2048];
  __shared__ float xs[32][132];
  const int tid = threadIdx.x;
  const int dt = tid & 15;
  const int grp = tid >> 4;
  const int half = blockIdx.y;
  const int base = blockIdx.x * 32;
  const float4* __restrict__ W4 = (const float4*)W;

  for (int i = tid; i < 2048; i += 256) {
    int k = i >> 4, d = i & 15;
    Ws4[i] = W4[(k << 5) + (half << 4) + d];
  }
  const float4 a4 = ((const float4*)avec)[(half << 4) + dt];
  const float am[4] = {a4.x, a4.y, a4.z, a4.w};

  float m[2][4], den[2][4], num[2][4];
#pragma unroll
  for (int g = 0; g < 2; ++g)
#pragma unroll
    for (int c = 0; c < 4; ++c) { m[g][c] = -3.0e38f; den[g][c] = 0.f; num[g][c] = 0.f; }

#pragma unroll
  for (int l = 0; l < L; ++l) {
    __syncthreads();
    const unsigned* __restrict__ Lh = args.layer[l];
    for (int i = tid; i < 2048; i += 256) {
      int r = i >> 6, c2 = i & 63;
      int node = base + r;
      unsigned v = (node < n) ? Lh[(size_t)node * 64 + c2] : 0u;
      xs[r][(c2 << 1)] = bf_lo(v);
      xs[r][(c2 << 1) + 1] = bf_hi(v);
    }
    __syncthreads();
    float s0[4] = {0.f, 0.f, 0.f, 0.f}, s1[4] = {0.f, 0.f, 0.f, 0.f};
#pragma unroll 4
    for (int k = 0; k < 128; ++k) {
      float4 w = Ws4[(k << 4) + dt];
      float x0 = xs[grp][k];
      float x1 = xs[grp + 16][k];
      s0[0] = fmaf(x0, w.x, s0[0]); s0[1] = fmaf(x0, w.y, s0[1]);
      s0[2] = fmaf(x0, w.z, s0[2]); s0[3] = fmaf(x0, w.w, s0[3]);
      s1[0] = fmaf(x1, w.x, s1[0]); s1[1] = fmaf(x1, w.y, s1[1]);
      s1[2] = fmaf(x1, w.z, s1[2]); s1[3] = fmaf(x1, w.w, s1[3]);
    }
    float c = args.coef[l];
    float4 t0 = *(const float4*)&xs[grp][(half << 6) + (dt << 2)];
    float4 t1 = *(const float4*)&xs[grp + 16][(half << 6) + (dt << 2)];
    const float tv0[4] = {t0.x, t0.y, t0.z, t0.w};
    const float tv1[4] = {t1.x, t1.y, t1.z, t1.w};
#pragma unroll
    for (int ch = 0; ch < 4; ++ch) {
      osm_upd(m[0][ch], den[0][ch], num[0][ch], c * s0[ch] * am[ch], c * tv0[ch]);
      osm_upd(m[1][ch], den[1][ch], num[1][ch], c * s1[ch] * am[ch], c * tv1[ch]);
    }
  }
#pragma unroll
  for (int g = 0; g < 2; ++g) {
    int node = base + grp + g * 16;
    if (node >= n) continue;
    float4 o;
    o.x = num[g][0] / den[g][0];
    o.y = num[g][1] / den[g][1];
    o.z = num[g][2] / den[g][2];
    o.w = num[g][3] / den[g][3];
    size_t oi = (size_t)node * 32 + (half << 4) + dt;
    float4* op = (float4*)out + oi;
    if (beta) {
      float4 pv = *op;
      float ex = 0.f, ey = 0.f, ez = 0.f, ew = 0.f;
      if (extra) {
        uint2 ev = ((const uint2*)extra)[oi];
        ex = bf_lo(ev.x); ey = bf_hi(ev.x); ez = bf_lo(ev.y); ew = bf_hi(ev.y);
      }
      o.x = pv.x + out_scale * o.x + escale * ex;
      o.y = pv.y + out_scale * o.y + escale * ey;
      o.z = pv.z + out_scale * o.z + escale * ez;
      o.w = pv.w + out_scale * o.w + escale * ew;
    } else {
      o.x *= out_scale; o.y *= out_scale; o.z *= out_scale; o.w *= out_scale;
    }
    *op = o;
  }
}

inline dim3 g1(long n) { return dim3((unsigned)((n + 255) / 256)); }

} // namespace

extern "C" void kernel_launch(void* const* d_in, const int* in_sizes, int n_in,
                              void* d_out, int out_size, void* d_ws, size_t ws_size,
                              hipStream_t stream) {
  const int* ug_u = (const int*)d_in[0];
  const int* ug_g = (const int*)d_in[1];
  const int* aS[3] = {(const int*)d_in[2], (const int*)d_in[4], (const int*)d_in[6]};
  const int* aD[3] = {(const int*)d_in[3], (const int*)d_in[5], (const int*)d_in[7]};
  const int* oS = (const int*)d_in[8];
  const int* oD = (const int*)d_in[9];
  const float* ue    = (const float*)d_in[10];
  const float* ie    = (const float*)d_in[11];
  const float* W_and = (const float*)d_in[12];
  const float* a_and = (const float*)d_in[13];
  const float* W_or  = (const float*)d_in[14];
  const float* a_or  = (const float*)d_in[15];
  const float* wedge = (const float*)d_in[16];
  const float* wnode = (const float*)d_in[17];

  // ---- workspace carve-up ----
  char* basep = (char*)d_ws;
  size_t boff_ = 0;
  auto alloc = [&](size_t bytes) -> void* {
    void* r = basep + boff_;
    boff_ += (bytes + 15) & ~(size_t)15;
    return r;
  };

  const int NCNT = NU + 9 * NI;
  int* cnt_all = (int*)alloc((size_t)NCNT * 4);
  float* inv_all = (float*)alloc((size_t)NCNT * 4);
  int* cU = cnt_all;
  int* cG = cU + NU;
  int* cAs[3], *cAd[3];
  { int* p = cG + NI;
    for (int i = 0; i < 3; ++i) { cAs[i] = p; p += NI; cAd[i] = p; p += NI; } }
  int* cOs = cAd[2] + NI;
  int* cOd = cOs + NI;
  float* invU = inv_all;
  float* invG = invU + NU;
  float* iAo[3], *iAi[3];
  { float* p = invG + NI;
    for (int i = 0; i < 3; ++i) { iAo[i] = p; p += NI; iAi[i] = p; p += NI; } }
  float* iOo = iAi[2] + NI;
  float* iOi = iOo + NI;

  int* oUGu = (int*)alloc((size_t)(NU + 1) * 4);
  int* oUGg = (int*)alloc((size_t)(NI + 1) * 4);
  int* oAnd[3]; for (int i = 0; i < 3; ++i) oAnd[i] = (int*)alloc((size_t)(NI + 1) * 4);
  int* oOr = (int*)alloc((size_t)(NI + 1) * 4);
  int* curUGu = (int*)alloc((size_t)(NU + 1) * 4);
  int* curUGg = (int*)alloc((size_t)(NI + 1) * 4);
  int* curAnd[3]; for (int i = 0; i < 3; ++i) curAnd[i] = (int*)alloc((size_t)(NI + 1) * 4);
  int* curOr = (int*)alloc((size_t)(NI + 1) * 4);

  ushort_t* sUGu = (ushort_t*)alloc((size_t)EUG * 2);
  float* wUGu = (float*)alloc((size_t)EUG * 4);
  ushort_t* sUGg = (ushort_t*)alloc((size_t)EUG * 2);
  ushort_t* sAnd[3]; for (int i = 0; i < 3; ++i) sAnd[i] = (ushort_t*)alloc((size_t)EAND * 2);
  ushort_t* sOr = (ushort_t*)alloc((size_t)EOR * 2);

  // bf16 tables (row = 64 uints = 256 B)
  unsigned* ieh = (unsigned*)alloc((size_t)NI * 64 * 4);
  unsigned* ueh = (unsigned*)alloc((size_t)NU * 64 * 4);
  unsigned* hu1 = (unsigned*)alloc((size_t)NU * 64 * 4);
  unsigned* hg1 = (unsigned*)alloc((size_t)NI * 64 * 4);
  unsigned* hg2 = (unsigned*)alloc((size_t)NI * 64 * 4);
  unsigned* ab[6]; for (int i = 0; i < 6; ++i) ab[i] = (unsigned*)alloc((size_t)NI * 64 * 4);
  unsigned* ob[3]; for (int i = 0; i < 3; ++i) ob[i] = (unsigned*)alloc((size_t)NI * 64 * 4);

  float* out_hu = (float*)d_out;
  float* out_game = out_hu + (size_t)NU * D;

  // ---- zero counters ----
  hipMemsetAsync(cnt_all, 0, (size_t)NCNT * 4, stream);

  // ---- fused histograms + bf16 conversion ----
  HistoAll H{};
  {
    struct Arr { const int* idx; int* cnt; int E; int R; };
    Arr arrs[10] = {
      {ug_u, cU, EUG, NU}, {ug_g, cG, EUG, NI},
      {aS[0], cAs[0], EAND, NI}, {aD[0], cAd[0], EAND, NI},
      {aS[1], cAs[1], EAND, NI}, {aD[1], cAd[1], EAND, NI},
      {aS[2], cAs[2], EAND, NI}, {aD[2], cAd[2], EAND, NI},
      {oS, cOs, EOR, NI}, {oD, cOd, EOR, NI},
    };
    int nu = 0, bb = 0;
    for (int i = 0; i < 10; ++i) {
      int npass = (arrs[i].R + HW - 1) / HW;
      int win = (arrs[i].R + npass - 1) / npass;
      for (int p = 0; p < npass; ++p) {
        H.u[nu] = {arrs[i].idx, arrs[i].cnt, arrs[i].E,
                   p * win, min((p + 1) * win, arrs[i].R)};
        H.blkbase[nu] = bb;
        bb += HNB;
        ++nu;
      }
    }
    H.nunits = nu;
    H.blkbase[nu] = bb;
    H.nhisto = bb;
    H.a = ie; H.ah = ieh; H.n2a = (long)NI * 64;
    H.b = ue; H.bh = ueh; H.n2b = (long)NU * 64;
    int ncvt = 1360;
    histo_cvt_k<<<dim3(bb + ncvt), 1024, 0, stream>>>(H);
  }

  // ---- node-level scans (off + cur) + norms, fused ----
  ScanAll SA{};
  SA.s[0] = {cU, oUGu, curUGu, NU};
  SA.s[1] = {cG, oUGg, curUGg, NI};
  for (int i = 0; i < 3; ++i) SA.s[2 + i] = {cAd[i], oAnd[i], curAnd[i], NI};
  SA.s[5] = {cOd, oOr, curOr, NI};
  SA.cnt_all = cnt_all; SA.inv_all = inv_all; SA.ncnt = NCNT;
  exscan_norms_k<<<dim3(6 + (NCNT + 1023) / 1024), 1024, 0, stream>>>(SA);

  // ---- windowed CSR fills ----
  FillWin F{};
  {
    const int* ds[6] = {ug_u, ug_g, aD[0], aD[1], aD[2], oD};
    const int* ss[6] = {ug_g, ug_u, aS[0], aS[1], aS[2], oS};
    int* cs[6] = {curUGu, curUGg, curAnd[0], curAnd[1], curAnd[2], curOr};
    ushort_t* os[6] = {sUGu, sUGg, sAnd[0], sAnd[1], sAnd[2], sOr};
    int ns[6] = {EUG, EUG, EAND, EAND, EAND, EOR};
    int bb = 0;
    for (int i = 0; i < 6; ++i) {
      F.dst[i] = ds[i]; F.src[i] = ss[i]; F.cur[i] = cs[i]; F.csrc[i] = os[i]; F.n[i] = ns[i];
      F.blkbase[i] = bb; bb += (ns[i] + 255) / 256;
    }
    F.blkbase[6] = bb;
    F.cwt = wUGu; F.invS0 = invG; F.wn0 = wnode; F.we0 = wedge;
  }
  const int nodecount[6] = {NU, NI, NI, NI, NI, NI};
  for (int p = 0; p < NPASS; ++p) {
    for (int i = 0; i < 6; ++i) {
      int w = (nodecount[i] + NPASS - 1) / NPASS;
      F.wbeg[i] = p * w;
      F.wend[i] = min((p + 1) * w, nodecount[i]);
    }
    fill_win_k<<<dim3(F.blkbase[6]), 256, 0, stream>>>(F);
  }

  // ---- gathers (multi-job, 6 jobs per launch) ----
  auto launch_bg = [&](GJob* jobs, const int* rows, int nj) {
    GJobs J{};
    int tot = 0;
    for (int k = 0; k < nj; ++k) {
      J.j[k] = jobs[k];
      J.j[k].rbeg = tot;
      tot += rows[k];
    }
    for (int k = nj; k < 6; ++k) { J.j[k] = J.j[0]; J.j[k].rbeg = 0x7fffffff; }
    J.total = tot;
    gather_multi_k<<<dim3((tot + 3) / 4), 256, 0, stream>>>(J);
  };

  // G1: hu1<-ieh (UGu), hg1<-ueh (UGg), ab0..2<-ieh (AND), ob0<-ieh (OR)
  {
    GJob js[6] = {
      {ieh, oUGu, sUGu, wUGu, nullptr, invU, hu1, nullptr, 0},
      {ueh, oUGg, sUGg, nullptr, invU, invG, hg1, nullptr, 0},
      {ieh, oAnd[0], sAnd[0], nullptr, iAo[0], iAi[0], ab[0], nullptr, 0},
      {ieh, oAnd[1], sAnd[1], nullptr, iAo[1], iAi[1], ab[1], nullptr, 0},
      {ieh, oAnd[2], sAnd[2], nullptr, iAo[2], iAi[2], ab[2], nullptr, 0},
      {ieh, oOr, sOr, nullptr, iOo, iOi, ob[0], nullptr, 0},
    };
    const int rows[6] = {NU, NI, NI, NI, NI, NI};
    launch_bg(js, rows, 6);
  }
  // G2: out_hu<-hg1 (fp32 out), hg2<-hu1, ab3..5<-ab0..2, ob1<-ob0
  {
    GJob js[6] = {
      {hg1, oUGu, sUGu, wUGu, nullptr, invU, nullptr, out_hu, 0},
      {hu1, oUGg, sUGg, nullptr, invU, invG, hg2, nullptr, 0},
      {ab[0], oAnd[0], sAnd[0], nullptr, iAo[0], iAi[0], ab[3], nullptr, 0},
      {ab[1], oAnd[1], sAnd[1], nullptr, iAo[1], iAi[1], ab[4], nullptr, 0},
      {ab[2], oAnd[2], sAnd[2], nullptr, iAo[2], iAi[2], ab[5], nullptr, 0},
      {ob[0], oOr, sOr, nullptr, iOo, iOi, ob[1], nullptr, 0},
    };
    const int rows[6] = {NU, NI, NI, NI, NI, NI};
    launch_bg(js, rows, 6);
  }
  // G3: ob2<-ob1
  {
    GJob js[1] = {{ob[1], oOr, sOr, nullptr, iOo, iOi, ob[2], nullptr, 0}};
    const int rows[1] = {NI};
    launch_bg(js, rows, 1);
  }

  const float w_or = 80.0f / 82.0f;
  const float w_and = w_or / 80.0f;   // = 1/82
  const float w_self = w_and;

  // ---- layer attention ----
  AttnArgs aa{};
  aa.layer[0] = ieh;
  for (int i = 0; i < 6; ++i) aa.layer[1 + i] = ab[i];
  for (int i = 0; i < 7; ++i) aa.coef[i] = 1.0f;
  attn_k<7><<<dim3((NI + 31) / 32, 2), 256, 0, stream>>>(
      aa, W_and, a_and, out_game, w_and, 0, nullptr, 0.f, NI);

  AttnArgs ao{};
  ao.layer[0] = ieh; ao.layer[1] = ob[0]; ao.layer[2] = ob[1]; ao.layer[3] = ob[2];
  ao.coef[0] = 1.0f; ao.coef[1] = 0.6f; ao.coef[2] = 0.8f; ao.coef[3] = 1.0f;
  attn_k<4><<<dim3((NI + 31) / 32, 2), 256, 0, stream>>>(
      ao, W_or, a_or, out_game, w_or, 1, hg2, w_self, NI);
}